// Round 11
// baseline (203.237 us; speedup 1.0000x reference)
//
#include <hip/hip_runtime.h>
#include <hip/hip_bf16.h>

// EncoderBlock: B=2, N=4096, D=256, H=8, HD=32, DFF=1024.
// I/O fp32; internal bf16 MFMA. r10 pipeline (197.8us) +
//  - Schraudolph exp2 (fma+cvt+perm, self-normalizing via MFMA-ones l)
//  - split-K combine fused into Wo's A-staging (combine kernel removed)
#define Bb 2
#define Nn 4096
#define Dd 256
#define Hh 8
#define HDh 32
#define DFFd 1024
#define MT (Bb*Nn)   // 8192 rows
#define Tt ((size_t)MT * Dd)
#define SPLIT 4
#define KVB (Nn / SPLIT)
#define NSTP (KVB / 64)   // 16

typedef __attribute__((ext_vector_type(8))) short short8;
typedef __attribute__((ext_vector_type(4))) float f32x4;
typedef __attribute__((address_space(1))) const unsigned int gu32;
typedef __attribute__((address_space(3))) unsigned int lu32;

__device__ __forceinline__ void gll16(const ushort* g, ushort* l) {
  // async global->LDS, 16B/lane; LDS dest = wave-uniform base + lane*16
  __builtin_amdgcn_global_load_lds((gu32*)g, (lu32*)l, 16, 0, 0);
}
__device__ __forceinline__ float bf2f(ushort u){
  union { unsigned int i; float f; } v; v.i = ((unsigned int)u) << 16; return v.f;
}
__device__ __forceinline__ ushort f2bf(float f){           // RNE
  union { float f; unsigned int i; } v; v.f = f;
  unsigned int r = v.i + 0x7fffu + ((v.i >> 16) & 1u);
  return (ushort)(r >> 16);
}
__device__ __forceinline__ int ars(int r){ return r * 64 + (r >> 3) * 32; }

// ---- layernorm helper: 4 rows per wave --------------------------------------
__device__ __forceinline__ void ln_rows4(const float* __restrict__ x,
                                         ushort* __restrict__ out, int row0,
                                         int wave, int lane)
{
  #pragma unroll
  for (int r = 0; r < 4; r++) {
    const int row = row0 + wave * 4 + r;
    const float4 u = *(const float4*)(x + (size_t)row * Dd + lane * 4);
    float s1 = u.x + u.y + u.z + u.w;
    float s2 = u.x*u.x + u.y*u.y + u.z*u.z + u.w*u.w;
    #pragma unroll
    for (int m = 1; m < 64; m <<= 1) { s1 += __shfl_xor(s1, m, 64); s2 += __shfl_xor(s2, m, 64); }
    const float mean = s1 * (1.0f / Dd);
    float var = s2 * (1.0f / Dd) - mean * mean;
    var = var < 0.f ? 0.f : var;
    const float inv = 1.0f / (sqrtf(var) + 1e-6f);
    ushort4 o;
    o.x = f2bf((u.x - mean) * inv); o.y = f2bf((u.y - mean) * inv);
    o.z = f2bf((u.z - mean) * inv); o.w = f2bf((u.w - mean) * inv);
    *(ushort4*)(out + (size_t)row * Dd + lane * 4) = o;
  }
}

// ---- p0: weight transpose prep (blocks 0..192) + LN1 (all 512 blocks) ------
__global__ __launch_bounds__(256) void p0_kernel(
    const float* __restrict__ Wq, const float* __restrict__ Wk,
    const float* __restrict__ Wv, const float* __restrict__ Wo,
    const float* __restrict__ W1, const float* __restrict__ W2,
    const float* __restrict__ bq, const float* __restrict__ bk,
    const float* __restrict__ bv, ushort* __restrict__ wt,
    float* __restrict__ bqkv, const float* __restrict__ x,
    ushort* __restrict__ xn1)
{
  const int bid = blockIdx.x, t = threadIdx.x;
  __shared__ __align__(16) ushort T[64][72];
  if (bid < 192) {
    const float* src; ushort* dst; int Nsrc, Kdst, kt, nt;
    if (bid < 64) {
      const int m = bid >> 4, tile = bid & 15;
      kt = tile >> 2; nt = tile & 3; Nsrc = 256; Kdst = 256;
      src = (m == 0 ? Wq : m == 1 ? Wk : m == 2 ? Wv : Wo);
      dst = (m == 3) ? (wt + 196608) : (wt + m * 65536);
    } else if (bid < 128) {
      const int tile = bid - 64; kt = tile >> 4; nt = tile & 15;
      Nsrc = 1024; Kdst = 256; src = W1; dst = wt + 262144;
    } else {
      const int tile = bid - 128; kt = tile >> 2; nt = tile & 3;
      Nsrc = 256; Kdst = 1024; src = W2; dst = wt + 524288;
    }
    const int k0 = kt * 64, n0 = nt * 64;
    const int cc = t & 15, rr = t >> 4;
    #pragma unroll
    for (int pass = 0; pass < 4; pass++) {
      const int k = rr + pass * 16;
      const float4 v = *(const float4*)(src + (size_t)(k0 + k) * Nsrc + n0 + cc * 4);
      T[cc * 4 + 0][k] = f2bf(v.x); T[cc * 4 + 1][k] = f2bf(v.y);
      T[cc * 4 + 2][k] = f2bf(v.z); T[cc * 4 + 3][k] = f2bf(v.w);
    }
    __syncthreads();
    const int nl = t >> 2, ks = (t & 3) * 16;
    const short8 a = *(const short8*)(&T[nl][ks]);
    const short8 b = *(const short8*)(&T[nl][ks + 8]);
    ushort* drow = dst + (size_t)(n0 + nl) * Kdst + k0 + ks;
    *(short8*)(drow) = a; *(short8*)(drow + 8) = b;
  } else if (bid == 192) {
    bqkv[t] = bq[t]; bqkv[256 + t] = bk[t]; bqkv[512 + t] = bv[t];
  }
  ln_rows4(x, xn1, bid * 16, t >> 6, t & 63);
}

// ---- LN2 (standalone) ------------------------------------------------------
__global__ __launch_bounds__(256) void ln_kernel(const float* __restrict__ x,
                                                 ushort* __restrict__ out)
{
  ln_rows4(x, out, blockIdx.x * 16, threadIdx.x >> 6, threadIdx.x & 63);
}

// ---- BMx64-tile MFMA GEMM, BK=64 gll16 double-buffer (r8 structure) --------
template<int EPI, int BM>
__global__ __launch_bounds__(256) void gemm_epi(
    const ushort* __restrict__ A, const ushort* __restrict__ BT,
    const float* __restrict__ bias, const float* __restrict__ res,
    void* __restrict__ outv, int N, int K)
{
  constexpr int MI = BM / 64;
  constexpr int AI = BM / 32;
  __shared__ __align__(16) ushort AsF[2][BM * 64 + (BM / 8) * 32];
  __shared__ __align__(16) ushort BsF[2][64 * 64 + 8 * 32];
  const int tid = threadIdx.x;
  const int wave = tid >> 6, lane = tid & 63;
  const int quad = lane >> 4, l15 = lane & 15;
  const int n0 = blockIdx.x * 64, m0 = blockIdx.y * BM;
  f32x4 acc[MI][4];
  #pragma unroll
  for (int mt = 0; mt < MI; mt++)
    #pragma unroll
    for (int nt = 0; nt < 4; nt++) acc[mt][nt] = (f32x4){0.f,0.f,0.f,0.f};
  const int srow = lane >> 3, scol = (lane & 7) * 8;
  const ushort* gA[AI];
  #pragma unroll
  for (int ai = 0; ai < AI; ai++)
    gA[ai] = A + (size_t)(m0 + ai * 32 + wave * 8 + srow) * K + scol;
  const ushort* gB[2];
  #pragma unroll
  for (int bi = 0; bi < 2; bi++)
    gB[bi] = BT + (size_t)(n0 + bi * 32 + wave * 8 + srow) * K + scol;
  int aoff[MI], boff[4];
  #pragma unroll
  for (int mt = 0; mt < MI; mt++) aoff[mt] = ars(wave * 16 * MI + mt * 16 + l15);
  #pragma unroll
  for (int nt = 0; nt < 4; nt++) boff[nt] = ars(nt * 16 + l15);
  #pragma unroll
  for (int ai = 0; ai < AI; ai++) gll16(gA[ai], &AsF[0][ars(ai * 32 + wave * 8)]);
  #pragma unroll
  for (int bi = 0; bi < 2; bi++) gll16(gB[bi], &BsF[0][ars(bi * 32 + wave * 8)]);
  __syncthreads();
  const int NC = K >> 6;
  int p = 0;
  for (int c = 0; c < NC; c++) {
    if (c + 1 < NC) {
      #pragma unroll
      for (int ai = 0; ai < AI; ai++)
        gll16(gA[ai] + (c + 1) * 64, &AsF[p ^ 1][ars(ai * 32 + wave * 8)]);
      #pragma unroll
      for (int bi = 0; bi < 2; bi++)
        gll16(gB[bi] + (c + 1) * 64, &BsF[p ^ 1][ars(bi * 32 + wave * 8)]);
    }
    #pragma unroll
    for (int kk = 0; kk < 2; kk++) {
      short8 af[MI];
      #pragma unroll
      for (int mt = 0; mt < MI; mt++)
        af[mt] = *(const short8*)(&AsF[p][aoff[mt] + kk * 32 + quad * 8]);
      #pragma unroll
      for (int nt = 0; nt < 4; nt++) {
        const short8 bf = *(const short8*)(&BsF[p][boff[nt] + kk * 32 + quad * 8]);
        #pragma unroll
        for (int mt = 0; mt < MI; mt++)
          acc[mt][nt] = __builtin_amdgcn_mfma_f32_16x16x32_bf16(af[mt], bf, acc[mt][nt], 0, 0, 0);
      }
    }
    __syncthreads();
    p ^= 1;
  }
  #pragma unroll
  for (int mt = 0; mt < MI; mt++) {
    const int row0 = m0 + wave * (16 * MI) + mt * 16 + quad * 4;
    #pragma unroll
    for (int nt = 0; nt < 4; nt++) {
      const int col = n0 + nt * 16 + l15;
      const float bv = bias[col];
      float c[4];
      #pragma unroll
      for (int i = 0; i < 4; i++) c[i] = acc[mt][nt][i] + bv;
      if (EPI == 0) {
        ushort* qkv = (ushort*)outv;
        const int w = col >> 8, cd = col & 255;
        const int h = cd >> 5, hd = cd & 31;
        const int b = row0 >> 12, n = row0 & (Nn - 1);
        if (w < 2) {
          const float sc2 = (w == 0) ? (1.4426950408889634f * 0.17677669529663687f) : 1.0f;
          ushort* dst = qkv + (size_t)w * Tt + ((size_t)((b * Hh + h) * Nn) + n) * HDh + hd;
          #pragma unroll
          for (int i = 0; i < 4; i++) dst[(size_t)i * HDh] = f2bf(c[i] * sc2);
        } else {   // V transposed: [b,h,hd,n]
          ushort4 pk;
          pk.x = f2bf(c[0]); pk.y = f2bf(c[1]); pk.z = f2bf(c[2]); pk.w = f2bf(c[3]);
          *(ushort4*)(qkv + 2 * Tt + ((size_t)((b * Hh + h) * HDh + hd)) * Nn + n) = pk;
        }
      } else if (EPI == 1) {
        float* out = (float*)outv;
        #pragma unroll
        for (int i = 0; i < 4; i++) {
          const size_t idx = (size_t)(row0 + i) * N + col;
          out[idx] = c[i] + res[idx];
        }
      } else {
        ushort* out = (ushort*)outv;
        #pragma unroll
        for (int i = 0; i < 4; i++) {
          const float t = tanhf(0.7978845608028654f * (c[i] + 0.044715f * c[i] * c[i] * c[i]));
          out[(size_t)(row0 + i) * N + col] = f2bf(0.5f * c[i] * (1.0f + t));
        }
      }
    }
  }
}

// ---- Wo GEMM with fused split-K combine in A-staging -----------------------
// A[m][k] = (sum_sp op_sp[bh][n][hd]) / (sum_sp l_sp[bh][n]); reg-staged into
// group-padded LDS; B via gll16 dbuf; ONE barrier per 64-k chunk.
__global__ __launch_bounds__(256) void wo_fused(
    const ushort* __restrict__ op0, const ushort* __restrict__ op1,
    const ushort* __restrict__ op2, const ushort* __restrict__ op3,
    const float* __restrict__ lp, const ushort* __restrict__ BT,
    const float* __restrict__ bias, const float* __restrict__ res,
    float* __restrict__ out)
{
  __shared__ __align__(16) ushort AsF[2][64 * 64 + 8 * 32];
  __shared__ __align__(16) ushort BsF[2][64 * 64 + 8 * 32];
  const int tid = threadIdx.x;
  const int wave = tid >> 6, lane = tid & 63;
  const int quad = lane >> 4, l15 = lane & 15;
  const int n0 = blockIdx.x * 64, m0 = blockIdx.y * 64;
  f32x4 acc[4];
  #pragma unroll
  for (int nt = 0; nt < 4; nt++) acc[nt] = (f32x4){0.f,0.f,0.f,0.f};
  const int srow = lane >> 3, scol = (lane & 7) * 8;
  const int mrow[2] = { m0 + wave * 8 + srow, m0 + 32 + wave * 8 + srow };
  const ushort* gB[2];
  #pragma unroll
  for (int bi = 0; bi < 2; bi++)
    gB[bi] = BT + (size_t)(n0 + bi * 32 + wave * 8 + srow) * Dd + scol;
  const int aoff = ars(wave * 16 + l15);
  int boff[4];
  #pragma unroll
  for (int nt = 0; nt < 4; nt++) boff[nt] = ars(nt * 16 + l15);
  // combine-loader: one 8-elem group of A for chunk c, sub-row ai
  auto combineA = [&](int c, int ai) -> short8 {
    const int m = mrow[ai];
    const int k = c * 64 + scol;
    const int b = m >> 12, n = m & (Nn - 1);
    const int bh = b * Hh + (k >> 5), hd = k & 31;
    const size_t off = ((size_t)bh * Nn + n) * HDh + hd;
    const short8 u0 = *(const short8*)(op0 + off);
    const short8 u1 = *(const short8*)(op1 + off);
    const short8 u2 = *(const short8*)(op2 + off);
    const short8 u3 = *(const short8*)(op3 + off);
    const size_t ln = (size_t)bh * Nn + n;
    const float inv = 1.0f / (lp[ln] + lp[65536 + ln] + lp[131072 + ln] + lp[196608 + ln]);
    short8 r;
    #pragma unroll
    for (int j = 0; j < 8; j++)
      r[j] = (short)f2bf((bf2f((ushort)u0[j]) + bf2f((ushort)u1[j]) +
                          bf2f((ushort)u2[j]) + bf2f((ushort)u3[j])) * inv);
    return r;
  };
  short8 ar0 = combineA(0, 0), ar1 = combineA(0, 1);
  gll16(gB[0], &BsF[0][ars(wave * 8)]);
  gll16(gB[1], &BsF[0][ars(32 + wave * 8)]);
  int p = 0;
  for (int c = 0; c < 4; c++) {
    *(short8*)(&AsF[p][ars(wave * 8 + srow) + scol])      = ar0;
    *(short8*)(&AsF[p][ars(32 + wave * 8 + srow) + scol]) = ar1;
    __syncthreads();   // A visible; drains B(c) gll (flight = prev MFMA phase)
    if (c + 1 < 4) {
      gll16(gB[0] + (c + 1) * 64, &BsF[p ^ 1][ars(wave * 8)]);
      gll16(gB[1] + (c + 1) * 64, &BsF[p ^ 1][ars(32 + wave * 8)]);
      ar0 = combineA(c + 1, 0); ar1 = combineA(c + 1, 1);
    }
    #pragma unroll
    for (int kk = 0; kk < 2; kk++) {
      const short8 af = *(const short8*)(&AsF[p][aoff + kk * 32 + quad * 8]);
      #pragma unroll
      for (int nt = 0; nt < 4; nt++) {
        const short8 bf = *(const short8*)(&BsF[p][boff[nt] + kk * 32 + quad * 8]);
        acc[nt] = __builtin_amdgcn_mfma_f32_16x16x32_bf16(af, bf, acc[nt], 0, 0, 0);
      }
    }
    p ^= 1;
  }
  const int row0 = m0 + wave * 16 + quad * 4;
  #pragma unroll
  for (int nt = 0; nt < 4; nt++) {
    const int col = n0 + nt * 16 + l15;
    const float bv = bias[col];
    #pragma unroll
    for (int i = 0; i < 4; i++) {
      const size_t idx = (size_t)(row0 + i) * Dd + col;
      out[idx] = acc[nt][i] + bv + res[idx];
    }
  }
}

// ---- Flash attention: split-K(4), q=64/wave, bf16 partial O + fp32 l -------
// Softmax via Schraudolph exp2: p-bits = (int)fma(s, 2^23, B); hi16 = bf16 p.
// +-3% per-weight spread but SELF-NORMALIZING: l is MFMA-ones-accumulated
// from the same packed P, so O = sum(p'v)/sum(p'); residual error averages
// down by sqrt(N_eff) >> 30.
__global__ __launch_bounds__(256, 4) void attn_kernel(
    const ushort* __restrict__ qp, const ushort* __restrict__ kp,
    const ushort* __restrict__ vtg, ushort* __restrict__ op0,
    ushort* __restrict__ op1, ushort* __restrict__ op2,
    ushort* __restrict__ op3, float* __restrict__ lp)
{
  __shared__ __align__(16) ushort Ks[2][64][32];   // K tile [kv][d] (gll16)
  __shared__ __align__(16) ushort Vt[2][32][72];   // V^T tile [d][kv] (reg-staged)
  __shared__ __align__(16) ushort Ps[4][64][40];   // per-wave P [q][kv-half]
  const int tid = threadIdx.x;
  const int wave = tid >> 6, lane = tid & 63;
  const int quad = lane >> 4, l15 = lane & 15;
  const int qtb = blockIdx.x, bh = blockIdx.y, sp = blockIdx.z;
  const size_t base = (size_t)bh * Nn * HDh;
  const int q0 = qtb * 256 + wave * 64;
  short8 qf[4];
  #pragma unroll
  for (int qt = 0; qt < 4; qt++)
    qf[qt] = *(const short8*)(qp + base + (size_t)(q0 + qt * 16 + l15) * HDh + quad * 8);
  const int kv0 = sp * KVB;
  const ushort* kg = kp + base + (size_t)(kv0 + wave * 16 + (lane >> 2)) * HDh + (lane & 3) * 8;
  const int vr = tid >> 3, vc = (tid & 7) * 8;
  const ushort* vg = vtg + base + (size_t)vr * Nn + kv0 + vc;
  ushort* psw = &Ps[wave][0][0];
  f32x4 o[2][4], ol[4];
  #pragma unroll
  for (int qt = 0; qt < 4; qt++) {
    o[0][qt] = (f32x4){0,0,0,0}; o[1][qt] = (f32x4){0,0,0,0};
    ol[qt] = (f32x4){0,0,0,0};
  }
  const short one = (short)0x3F80;
  const short8 ones = {one,one,one,one,one,one,one,one};
  const f32x4 zero4 = {0,0,0,0};
  const float SA = 8388608.0f;        // 2^23
  const float SB = 1065102389.0f;     // (127<<23) - minimax bias (~3% two-sided)
  gll16(kg, &Ks[0][wave * 16][0]);
  int4 vreg = *(const int4*)vg;
  *(int4*)(&Vt[0][vr][vc]) = vreg;
  vreg = *(const int4*)(vg + 64);
  __syncthreads();
  #pragma unroll 2
  for (int step = 0; step < NSTP; step++) {
    const int p = step & 1;
    if (step + 1 < NSTP) {
      gll16(kg + (size_t)(step + 1) * 64 * HDh, &Ks[p ^ 1][wave * 16][0]);
      *(int4*)(&Vt[p ^ 1][vr][vc]) = vreg;
    }
    if (step + 2 < NSTP) vreg = *(const int4*)(vg + (size_t)(step + 2) * 64);
    #pragma unroll
    for (int half = 0; half < 2; half++) {
      #pragma unroll
      for (int nt2 = 0; nt2 < 2; nt2++) {
        const int nt = half * 2 + nt2;
        const short8 kf = *(const short8*)(&Ks[p][nt * 16 + l15][quad * 8]);
        #pragma unroll
        for (int qt = 0; qt < 4; qt++) {
          const f32x4 s = __builtin_amdgcn_mfma_f32_16x16x32_bf16(kf, qf[qt], zero4, 0, 0, 0);
          const unsigned int i0 = (unsigned int)(int)fmaf(s[0], SA, SB);
          const unsigned int i1 = (unsigned int)(int)fmaf(s[1], SA, SB);
          const unsigned int i2 = (unsigned int)(int)fmaf(s[2], SA, SB);
          const unsigned int i3 = (unsigned int)(int)fmaf(s[3], SA, SB);
          uint2 pk;
          pk.x = __builtin_amdgcn_perm(i1, i0, 0x07060302u);
          pk.y = __builtin_amdgcn_perm(i3, i2, 0x07060302u);
          *(uint2*)(psw + (qt * 16 + l15) * 40 + nt2 * 16 + quad * 4) = pk;
        }
      }
      __builtin_amdgcn_wave_barrier();   // Ps wave-local; DS in-order per wave
      const short8 v0 = *(const short8*)(&Vt[p][l15][half * 32 + quad * 8]);
      const short8 v1 = *(const short8*)(&Vt[p][16 + l15][half * 32 + quad * 8]);
      #pragma unroll
      for (int qt = 0; qt < 4; qt++) {
        const short8 pb = *(const short8*)(psw + (qt * 16 + l15) * 40 + quad * 8);
        o[0][qt] = __builtin_amdgcn_mfma_f32_16x16x32_bf16(v0, pb, o[0][qt], 0, 0, 0);
        o[1][qt] = __builtin_amdgcn_mfma_f32_16x16x32_bf16(v1, pb, o[1][qt], 0, 0, 0);
        ol[qt]   = __builtin_amdgcn_mfma_f32_16x16x32_bf16(ones, pb, ol[qt], 0, 0, 0);
      }
      __builtin_amdgcn_wave_barrier();
    }
    __syncthreads();   // drains this step's prefetches (full phase elapsed)
  }
  lp[(size_t)sp * (16 * Nn) + (size_t)bh * Nn + q0 + lane] = ol[lane >> 4][0];
  ushort* ob = (sp == 0 ? op0 : sp == 1 ? op1 : sp == 2 ? op2 : op3);
  #pragma unroll
  for (int pass = 0; pass < 2; pass++) {
    #pragma unroll
    for (int qt2 = 0; qt2 < 2; qt2++) {
      const int qt = pass * 2 + qt2;
      #pragma unroll
      for (int dt = 0; dt < 2; dt++) {
        ushort4 pk;
        pk.x = f2bf(o[dt][qt][0]); pk.y = f2bf(o[dt][qt][1]);
        pk.z = f2bf(o[dt][qt][2]); pk.w = f2bf(o[dt][qt][3]);
        *(ushort4*)(psw + (qt2 * 16 + l15) * 40 + dt * 16 + quad * 4) = pk;
      }
    }
    __builtin_amdgcn_wave_barrier();
    #pragma unroll
    for (int j = 0; j < 2; j++) {
      const int row = j * 16 + (lane >> 2);
      const short8 ov = *(const short8*)(psw + row * 40 + (lane & 3) * 8);
      const int q = q0 + pass * 32 + row;
      *(short8*)(ob + ((size_t)bh * Nn + q) * HDh + (lane & 3) * 8) = ov;
    }
    __builtin_amdgcn_wave_barrier();
  }
}

extern "C" void kernel_launch(void* const* d_in, const int* in_sizes, int n_in,
                              void* d_out, int out_size, void* d_ws, size_t ws_size,
                              hipStream_t stream)
{
  const float* x  = (const float*)d_in[0];
  const float* Wq = (const float*)d_in[1];
  const float* bq = (const float*)d_in[2];
  const float* Wk = (const float*)d_in[3];
  const float* bk = (const float*)d_in[4];
  const float* Wv = (const float*)d_in[5];
  const float* bv = (const float*)d_in[6];
  const float* Wo = (const float*)d_in[7];
  const float* bo = (const float*)d_in[8];
  const float* W1 = (const float*)d_in[9];
  const float* b1 = (const float*)d_in[10];
  const float* W2 = (const float*)d_in[11];
  const float* b2 = (const float*)d_in[12];

  char* ws = (char*)d_ws;
  ushort* wt    = (ushort*)ws;                       // 786432 bf16
  ushort* wtqkv = wt;
  ushort* wto   = wt + 196608;
  ushort* wt1   = wt + 262144;
  ushort* wt2   = wt + 524288;
  float*  bqkv  = (float*)(ws + 786432 * 2);
  ushort* s0    = (ushort*)(ws + 786432 * 2 + 4096); // 4 MiB slots
  ushort* s1    = s0 + Tt;                           // q [b,h,n,hd] (scaled)
  ushort* s2    = s1 + Tt;                           // k [b,h,n,hd]
  ushort* s3    = s2 + Tt;                           // v^T [b,h,hd,n]
  float*  xsk   = (float*)(s3 + Tt);                 // fp32 8 MiB
  ushort* xn2   = (ushort*)(xsk + Tt);               // bf16 4 MiB
  float*  lp    = (float*)(xn2 + Tt);                // 512 KiB ws tail
  ushort* xn1   = s0;
  ushort* hid   = s0;                                // 16 MiB spans s0..s3
  // split-K partials (lifetimes: attn -> Wo-staging only):
  ushort* op0   = s0;                                // xn1 dead after QKV
  ushort* op1   = xn2;                               // LN2 writes xn2 AFTER Wo
  ushort* op2   = (ushort*)d_out;                    // W2 overwrites d_out last
  ushort* op3   = (ushort*)d_out + Tt;
  float*  outp  = (float*)d_out;

  const dim3 blk(256);
  hipLaunchKernelGGL(p0_kernel, dim3(512), blk, 0, stream,
                     Wq, Wk, Wv, Wo, W1, W2, bq, bk, bv, wt, bqkv, x, xn1);
  hipLaunchKernelGGL((gemm_epi<0,128>), dim3(12, 64), blk, 0, stream,
                     xn1, wtqkv, bqkv, (const float*)nullptr, (void*)s1, 768, Dd);

  hipLaunchKernelGGL(attn_kernel, dim3(Nn / 256, Bb * Hh, SPLIT), blk, 0, stream,
                     s1, s2, s3, op0, op1, op2, op3, lp);

  hipLaunchKernelGGL(wo_fused, dim3(4, 128), blk, 0, stream,
                     op0, op1, op2, op3, lp, wto, bo, x, xsk);
  hipLaunchKernelGGL(ln_kernel, dim3(MT / 16), blk, 0, stream, xsk, xn2);
  hipLaunchKernelGGL((gemm_epi<2,128>), dim3(16, 64), blk, 0, stream,
                     xn2, wt1, b1, (const float*)nullptr, (void*)hid, DFFd, Dd);
  hipLaunchKernelGGL((gemm_epi<1,64>), dim3(4, 128), blk, 0, stream,
                     hid, wt2, b2, xsk, (void*)outp, Dd, DFFd);
}

// Round 12
// 196.374 us; speedup vs baseline: 1.0349x; 1.0349x over previous
//
#include <hip/hip_runtime.h>
#include <hip/hip_bf16.h>

// EncoderBlock: B=2, N=4096, D=256, H=8, HD=32, DFF=1024.
// I/O fp32; internal bf16 MFMA.
// Best-known composition: r10 pipeline (197.8us: separate combine kernel,
// plain Wo GEMM) + r11's Schraudolph-softmax attention (54.4us, verified).
// wo_fused (r11) reverted: it duplicated combine work x4 across n-blocks.
#define Bb 2
#define Nn 4096
#define Dd 256
#define Hh 8
#define HDh 32
#define DFFd 1024
#define MT (Bb*Nn)   // 8192 rows
#define Tt ((size_t)MT * Dd)
#define SPLIT 4
#define KVB (Nn / SPLIT)
#define NSTP (KVB / 64)   // 16

typedef __attribute__((ext_vector_type(8))) short short8;
typedef __attribute__((ext_vector_type(4))) float f32x4;
typedef __attribute__((address_space(1))) const unsigned int gu32;
typedef __attribute__((address_space(3))) unsigned int lu32;

__device__ __forceinline__ void gll16(const ushort* g, ushort* l) {
  // async global->LDS, 16B/lane; LDS dest = wave-uniform base + lane*16
  __builtin_amdgcn_global_load_lds((gu32*)g, (lu32*)l, 16, 0, 0);
}
__device__ __forceinline__ float bf2f(ushort u){
  union { unsigned int i; float f; } v; v.i = ((unsigned int)u) << 16; return v.f;
}
__device__ __forceinline__ ushort f2bf(float f){           // RNE
  union { float f; unsigned int i; } v; v.f = f;
  unsigned int r = v.i + 0x7fffu + ((v.i >> 16) & 1u);
  return (ushort)(r >> 16);
}
__device__ __forceinline__ int ars(int r){ return r * 64 + (r >> 3) * 32; }

// ---- layernorm helper: 4 rows per wave --------------------------------------
__device__ __forceinline__ void ln_rows4(const float* __restrict__ x,
                                         ushort* __restrict__ out, int row0,
                                         int wave, int lane)
{
  #pragma unroll
  for (int r = 0; r < 4; r++) {
    const int row = row0 + wave * 4 + r;
    const float4 u = *(const float4*)(x + (size_t)row * Dd + lane * 4);
    float s1 = u.x + u.y + u.z + u.w;
    float s2 = u.x*u.x + u.y*u.y + u.z*u.z + u.w*u.w;
    #pragma unroll
    for (int m = 1; m < 64; m <<= 1) { s1 += __shfl_xor(s1, m, 64); s2 += __shfl_xor(s2, m, 64); }
    const float mean = s1 * (1.0f / Dd);
    float var = s2 * (1.0f / Dd) - mean * mean;
    var = var < 0.f ? 0.f : var;
    const float inv = 1.0f / (sqrtf(var) + 1e-6f);
    ushort4 o;
    o.x = f2bf((u.x - mean) * inv); o.y = f2bf((u.y - mean) * inv);
    o.z = f2bf((u.z - mean) * inv); o.w = f2bf((u.w - mean) * inv);
    *(ushort4*)(out + (size_t)row * Dd + lane * 4) = o;
  }
}

// ---- p0: weight transpose prep (blocks 0..192) + LN1 (all 512 blocks) ------
__global__ __launch_bounds__(256) void p0_kernel(
    const float* __restrict__ Wq, const float* __restrict__ Wk,
    const float* __restrict__ Wv, const float* __restrict__ Wo,
    const float* __restrict__ W1, const float* __restrict__ W2,
    const float* __restrict__ bq, const float* __restrict__ bk,
    const float* __restrict__ bv, ushort* __restrict__ wt,
    float* __restrict__ bqkv, const float* __restrict__ x,
    ushort* __restrict__ xn1)
{
  const int bid = blockIdx.x, t = threadIdx.x;
  __shared__ __align__(16) ushort T[64][72];
  if (bid < 192) {
    const float* src; ushort* dst; int Nsrc, Kdst, kt, nt;
    if (bid < 64) {
      const int m = bid >> 4, tile = bid & 15;
      kt = tile >> 2; nt = tile & 3; Nsrc = 256; Kdst = 256;
      src = (m == 0 ? Wq : m == 1 ? Wk : m == 2 ? Wv : Wo);
      dst = (m == 3) ? (wt + 196608) : (wt + m * 65536);
    } else if (bid < 128) {
      const int tile = bid - 64; kt = tile >> 4; nt = tile & 15;
      Nsrc = 1024; Kdst = 256; src = W1; dst = wt + 262144;
    } else {
      const int tile = bid - 128; kt = tile >> 2; nt = tile & 3;
      Nsrc = 256; Kdst = 1024; src = W2; dst = wt + 524288;
    }
    const int k0 = kt * 64, n0 = nt * 64;
    const int cc = t & 15, rr = t >> 4;
    #pragma unroll
    for (int pass = 0; pass < 4; pass++) {
      const int k = rr + pass * 16;
      const float4 v = *(const float4*)(src + (size_t)(k0 + k) * Nsrc + n0 + cc * 4);
      T[cc * 4 + 0][k] = f2bf(v.x); T[cc * 4 + 1][k] = f2bf(v.y);
      T[cc * 4 + 2][k] = f2bf(v.z); T[cc * 4 + 3][k] = f2bf(v.w);
    }
    __syncthreads();
    const int nl = t >> 2, ks = (t & 3) * 16;
    const short8 a = *(const short8*)(&T[nl][ks]);
    const short8 b = *(const short8*)(&T[nl][ks + 8]);
    ushort* drow = dst + (size_t)(n0 + nl) * Kdst + k0 + ks;
    *(short8*)(drow) = a; *(short8*)(drow + 8) = b;
  } else if (bid == 192) {
    bqkv[t] = bq[t]; bqkv[256 + t] = bk[t]; bqkv[512 + t] = bv[t];
  }
  ln_rows4(x, xn1, bid * 16, t >> 6, t & 63);
}

// ---- LN2 (standalone) ------------------------------------------------------
__global__ __launch_bounds__(256) void ln_kernel(const float* __restrict__ x,
                                                 ushort* __restrict__ out)
{
  ln_rows4(x, out, blockIdx.x * 16, threadIdx.x >> 6, threadIdx.x & 63);
}

// ---- BMx64-tile MFMA GEMM, BK=64 gll16 double-buffer (r8 structure) --------
template<int EPI, int BM>
__global__ __launch_bounds__(256) void gemm_epi(
    const ushort* __restrict__ A, const ushort* __restrict__ BT,
    const float* __restrict__ bias, const float* __restrict__ res,
    void* __restrict__ outv, int N, int K)
{
  constexpr int MI = BM / 64;
  constexpr int AI = BM / 32;
  __shared__ __align__(16) ushort AsF[2][BM * 64 + (BM / 8) * 32];
  __shared__ __align__(16) ushort BsF[2][64 * 64 + 8 * 32];
  const int tid = threadIdx.x;
  const int wave = tid >> 6, lane = tid & 63;
  const int quad = lane >> 4, l15 = lane & 15;
  const int n0 = blockIdx.x * 64, m0 = blockIdx.y * BM;
  f32x4 acc[MI][4];
  #pragma unroll
  for (int mt = 0; mt < MI; mt++)
    #pragma unroll
    for (int nt = 0; nt < 4; nt++) acc[mt][nt] = (f32x4){0.f,0.f,0.f,0.f};
  const int srow = lane >> 3, scol = (lane & 7) * 8;
  const ushort* gA[AI];
  #pragma unroll
  for (int ai = 0; ai < AI; ai++)
    gA[ai] = A + (size_t)(m0 + ai * 32 + wave * 8 + srow) * K + scol;
  const ushort* gB[2];
  #pragma unroll
  for (int bi = 0; bi < 2; bi++)
    gB[bi] = BT + (size_t)(n0 + bi * 32 + wave * 8 + srow) * K + scol;
  int aoff[MI], boff[4];
  #pragma unroll
  for (int mt = 0; mt < MI; mt++) aoff[mt] = ars(wave * 16 * MI + mt * 16 + l15);
  #pragma unroll
  for (int nt = 0; nt < 4; nt++) boff[nt] = ars(nt * 16 + l15);
  #pragma unroll
  for (int ai = 0; ai < AI; ai++) gll16(gA[ai], &AsF[0][ars(ai * 32 + wave * 8)]);
  #pragma unroll
  for (int bi = 0; bi < 2; bi++) gll16(gB[bi], &BsF[0][ars(bi * 32 + wave * 8)]);
  __syncthreads();
  const int NC = K >> 6;
  int p = 0;
  for (int c = 0; c < NC; c++) {
    if (c + 1 < NC) {
      #pragma unroll
      for (int ai = 0; ai < AI; ai++)
        gll16(gA[ai] + (c + 1) * 64, &AsF[p ^ 1][ars(ai * 32 + wave * 8)]);
      #pragma unroll
      for (int bi = 0; bi < 2; bi++)
        gll16(gB[bi] + (c + 1) * 64, &BsF[p ^ 1][ars(bi * 32 + wave * 8)]);
    }
    #pragma unroll
    for (int kk = 0; kk < 2; kk++) {
      short8 af[MI];
      #pragma unroll
      for (int mt = 0; mt < MI; mt++)
        af[mt] = *(const short8*)(&AsF[p][aoff[mt] + kk * 32 + quad * 8]);
      #pragma unroll
      for (int nt = 0; nt < 4; nt++) {
        const short8 bf = *(const short8*)(&BsF[p][boff[nt] + kk * 32 + quad * 8]);
        #pragma unroll
        for (int mt = 0; mt < MI; mt++)
          acc[mt][nt] = __builtin_amdgcn_mfma_f32_16x16x32_bf16(af[mt], bf, acc[mt][nt], 0, 0, 0);
      }
    }
    __syncthreads();
    p ^= 1;
  }
  #pragma unroll
  for (int mt = 0; mt < MI; mt++) {
    const int row0 = m0 + wave * (16 * MI) + mt * 16 + quad * 4;
    #pragma unroll
    for (int nt = 0; nt < 4; nt++) {
      const int col = n0 + nt * 16 + l15;
      const float bv = bias[col];
      float c[4];
      #pragma unroll
      for (int i = 0; i < 4; i++) c[i] = acc[mt][nt][i] + bv;
      if (EPI == 0) {
        ushort* qkv = (ushort*)outv;
        const int w = col >> 8, cd = col & 255;
        const int h = cd >> 5, hd = cd & 31;
        const int b = row0 >> 12, n = row0 & (Nn - 1);
        if (w < 2) {
          const float sc2 = (w == 0) ? (1.4426950408889634f * 0.17677669529663687f) : 1.0f;
          ushort* dst = qkv + (size_t)w * Tt + ((size_t)((b * Hh + h) * Nn) + n) * HDh + hd;
          #pragma unroll
          for (int i = 0; i < 4; i++) dst[(size_t)i * HDh] = f2bf(c[i] * sc2);
        } else {   // V transposed: [b,h,hd,n]
          ushort4 pk;
          pk.x = f2bf(c[0]); pk.y = f2bf(c[1]); pk.z = f2bf(c[2]); pk.w = f2bf(c[3]);
          *(ushort4*)(qkv + 2 * Tt + ((size_t)((b * Hh + h) * HDh + hd)) * Nn + n) = pk;
        }
      } else if (EPI == 1) {
        float* out = (float*)outv;
        #pragma unroll
        for (int i = 0; i < 4; i++) {
          const size_t idx = (size_t)(row0 + i) * N + col;
          out[idx] = c[i] + res[idx];
        }
      } else {
        ushort* out = (ushort*)outv;
        #pragma unroll
        for (int i = 0; i < 4; i++) {
          const float t = tanhf(0.7978845608028654f * (c[i] + 0.044715f * c[i] * c[i] * c[i]));
          out[(size_t)(row0 + i) * N + col] = f2bf(0.5f * c[i] * (1.0f + t));
        }
      }
    }
  }
}

// ---- Flash attention: split-K(4), q=64/wave, bf16 partial O + fp32 l -------
// Softmax via Schraudolph exp2: p-bits = (int)fma(s, 2^23, B); hi16 = bf16 p.
// +-3% per-weight spread but SELF-NORMALIZING: l is MFMA-ones-accumulated
// from the same packed P, so O = sum(p'v)/sum(p'); residual error averages
// down by sqrt(N_eff) >> 30.  [verified r11: absmax 0.03125]
__global__ __launch_bounds__(256, 4) void attn_kernel(
    const ushort* __restrict__ qp, const ushort* __restrict__ kp,
    const ushort* __restrict__ vtg, ushort* __restrict__ op0,
    ushort* __restrict__ op123, float* __restrict__ lp)
{
  __shared__ __align__(16) ushort Ks[2][64][32];   // K tile [kv][d] (gll16)
  __shared__ __align__(16) ushort Vt[2][32][72];   // V^T tile [d][kv] (reg-staged)
  __shared__ __align__(16) ushort Ps[4][64][40];   // per-wave P [q][kv-half]
  const int tid = threadIdx.x;
  const int wave = tid >> 6, lane = tid & 63;
  const int quad = lane >> 4, l15 = lane & 15;
  const int qtb = blockIdx.x, bh = blockIdx.y, sp = blockIdx.z;
  const size_t base = (size_t)bh * Nn * HDh;
  const int q0 = qtb * 256 + wave * 64;
  short8 qf[4];
  #pragma unroll
  for (int qt = 0; qt < 4; qt++)
    qf[qt] = *(const short8*)(qp + base + (size_t)(q0 + qt * 16 + l15) * HDh + quad * 8);
  const int kv0 = sp * KVB;
  const ushort* kg = kp + base + (size_t)(kv0 + wave * 16 + (lane >> 2)) * HDh + (lane & 3) * 8;
  const int vr = tid >> 3, vc = (tid & 7) * 8;
  const ushort* vg = vtg + base + (size_t)vr * Nn + kv0 + vc;
  ushort* psw = &Ps[wave][0][0];
  f32x4 o[2][4], ol[4];
  #pragma unroll
  for (int qt = 0; qt < 4; qt++) {
    o[0][qt] = (f32x4){0,0,0,0}; o[1][qt] = (f32x4){0,0,0,0};
    ol[qt] = (f32x4){0,0,0,0};
  }
  const short one = (short)0x3F80;
  const short8 ones = {one,one,one,one,one,one,one,one};
  const f32x4 zero4 = {0,0,0,0};
  const float SA = 8388608.0f;        // 2^23
  const float SB = 1065102389.0f;     // (127<<23) - minimax bias (~3% two-sided)
  gll16(kg, &Ks[0][wave * 16][0]);
  int4 vreg = *(const int4*)vg;
  *(int4*)(&Vt[0][vr][vc]) = vreg;
  vreg = *(const int4*)(vg + 64);
  __syncthreads();
  #pragma unroll 2
  for (int step = 0; step < NSTP; step++) {
    const int p = step & 1;
    if (step + 1 < NSTP) {
      gll16(kg + (size_t)(step + 1) * 64 * HDh, &Ks[p ^ 1][wave * 16][0]);
      *(int4*)(&Vt[p ^ 1][vr][vc]) = vreg;
    }
    if (step + 2 < NSTP) vreg = *(const int4*)(vg + (size_t)(step + 2) * 64);
    #pragma unroll
    for (int half = 0; half < 2; half++) {
      #pragma unroll
      for (int nt2 = 0; nt2 < 2; nt2++) {
        const int nt = half * 2 + nt2;
        const short8 kf = *(const short8*)(&Ks[p][nt * 16 + l15][quad * 8]);
        #pragma unroll
        for (int qt = 0; qt < 4; qt++) {
          const f32x4 s = __builtin_amdgcn_mfma_f32_16x16x32_bf16(kf, qf[qt], zero4, 0, 0, 0);
          const unsigned int i0 = (unsigned int)(int)fmaf(s[0], SA, SB);
          const unsigned int i1 = (unsigned int)(int)fmaf(s[1], SA, SB);
          const unsigned int i2 = (unsigned int)(int)fmaf(s[2], SA, SB);
          const unsigned int i3 = (unsigned int)(int)fmaf(s[3], SA, SB);
          uint2 pk;
          pk.x = __builtin_amdgcn_perm(i1, i0, 0x07060302u);
          pk.y = __builtin_amdgcn_perm(i3, i2, 0x07060302u);
          *(uint2*)(psw + (qt * 16 + l15) * 40 + nt2 * 16 + quad * 4) = pk;
        }
      }
      __builtin_amdgcn_wave_barrier();   // Ps wave-local; DS in-order per wave
      const short8 v0 = *(const short8*)(&Vt[p][l15][half * 32 + quad * 8]);
      const short8 v1 = *(const short8*)(&Vt[p][16 + l15][half * 32 + quad * 8]);
      #pragma unroll
      for (int qt = 0; qt < 4; qt++) {
        const short8 pb = *(const short8*)(psw + (qt * 16 + l15) * 40 + quad * 8);
        o[0][qt] = __builtin_amdgcn_mfma_f32_16x16x32_bf16(v0, pb, o[0][qt], 0, 0, 0);
        o[1][qt] = __builtin_amdgcn_mfma_f32_16x16x32_bf16(v1, pb, o[1][qt], 0, 0, 0);
        ol[qt]   = __builtin_amdgcn_mfma_f32_16x16x32_bf16(ones, pb, ol[qt], 0, 0, 0);
      }
      __builtin_amdgcn_wave_barrier();
    }
    __syncthreads();   // drains this step's prefetches (full phase elapsed)
  }
  lp[(size_t)sp * (16 * Nn) + (size_t)bh * Nn + q0 + lane] = ol[lane >> 4][0];
  ushort* ob = (sp == 0 ? op0 : op123 + (size_t)(sp - 1) * (16 * (size_t)Nn * HDh));
  #pragma unroll
  for (int pass = 0; pass < 2; pass++) {
    #pragma unroll
    for (int qt2 = 0; qt2 < 2; qt2++) {
      const int qt = pass * 2 + qt2;
      #pragma unroll
      for (int dt = 0; dt < 2; dt++) {
        ushort4 pk;
        pk.x = f2bf(o[dt][qt][0]); pk.y = f2bf(o[dt][qt][1]);
        pk.z = f2bf(o[dt][qt][2]); pk.w = f2bf(o[dt][qt][3]);
        *(ushort4*)(psw + (qt2 * 16 + l15) * 40 + dt * 16 + quad * 4) = pk;
      }
    }
    __builtin_amdgcn_wave_barrier();
    #pragma unroll
    for (int j = 0; j < 2; j++) {
      const int row = j * 16 + (lane >> 2);
      const short8 ov = *(const short8*)(psw + row * 40 + (lane & 3) * 8);
      const int q = q0 + pass * 32 + row;
      *(short8*)(ob + ((size_t)bh * Nn + q) * HDh + (lane & 3) * 8) = ov;
    }
    __builtin_amdgcn_wave_barrier();
  }
}

// ---- combine: O = (sum_sp Opart) / (sum_sp lpart), regather to [B,N,D] -----
__global__ __launch_bounds__(256) void attn_combine(
    const ushort* __restrict__ op0, const ushort* __restrict__ op123,
    const float* __restrict__ lp, ushort* __restrict__ attn)
{
  const int idx = blockIdx.x * 256 + threadIdx.x;   // 16bh x 4096n x 4(d8)
  const int d8 = idx & 3, n = (idx >> 2) & (Nn - 1), bh = idx >> 14;
  const size_t ln = (size_t)bh * Nn + n;
  float l = 0.f;
  #pragma unroll
  for (int sp = 0; sp < SPLIT; sp++) l += lp[(size_t)sp * (16 * Nn) + ln];
  const float inv = 1.0f / l;
  float acc[8];
  #pragma unroll
  for (int k = 0; k < 8; k++) acc[k] = 0.f;
  const size_t qoff = ln * HDh + d8 * 8;
  #pragma unroll
  for (int sp = 0; sp < SPLIT; sp++) {
    const ushort* src = (sp == 0 ? op0 : op123 + (size_t)(sp - 1) * (16 * (size_t)Nn * HDh)) + qoff;
    const short8 u = *(const short8*)src;
    #pragma unroll
    for (int k = 0; k < 8; k++) acc[k] += bf2f((ushort)u[k]);
  }
  short8 ov;
  #pragma unroll
  for (int k = 0; k < 8; k++) ov[k] = (short)f2bf(acc[k] * inv);
  const int b = bh >> 3, h = bh & 7;
  *(short8*)(attn + ((size_t)(b * Nn + n)) * Dd + h * HDh + d8 * 8) = ov;
}

extern "C" void kernel_launch(void* const* d_in, const int* in_sizes, int n_in,
                              void* d_out, int out_size, void* d_ws, size_t ws_size,
                              hipStream_t stream)
{
  const float* x  = (const float*)d_in[0];
  const float* Wq = (const float*)d_in[1];
  const float* bq = (const float*)d_in[2];
  const float* Wk = (const float*)d_in[3];
  const float* bk = (const float*)d_in[4];
  const float* Wv = (const float*)d_in[5];
  const float* bv = (const float*)d_in[6];
  const float* Wo = (const float*)d_in[7];
  const float* bo = (const float*)d_in[8];
  const float* W1 = (const float*)d_in[9];
  const float* b1 = (const float*)d_in[10];
  const float* W2 = (const float*)d_in[11];
  const float* b2 = (const float*)d_in[12];

  char* ws = (char*)d_ws;
  ushort* wt    = (ushort*)ws;                       // 786432 bf16
  ushort* wtqkv = wt;
  ushort* wto   = wt + 196608;
  ushort* wt1   = wt + 262144;
  ushort* wt2   = wt + 524288;
  float*  bqkv  = (float*)(ws + 786432 * 2);
  ushort* s0    = (ushort*)(ws + 786432 * 2 + 4096); // 4 MiB slots
  ushort* s1    = s0 + Tt;                           // q [b,h,n,hd] (scaled)
  ushort* s2    = s1 + Tt;                           // k [b,h,n,hd]
  ushort* s3    = s2 + Tt;                           // v^T [b,h,hd,n]
  float*  xsk   = (float*)(s3 + Tt);                 // fp32 8 MiB
  ushort* xn2   = (ushort*)(xsk + Tt);               // bf16 4 MiB
  ushort* xn1   = s0;
  ushort* hid   = s0;                                // 16 MiB spans s0..s3
  ushort* op0   = s0;                                // Opart sp0 (xn1 dead)
  ushort* op123 = (ushort*)xsk;                      // sp1..sp3 (12 MiB)
  float*  lp    = (float*)d_out;                     // scratch in d_out
  ushort* attnb = (ushort*)((char*)d_out + (4u << 20));
  float*  outp  = (float*)d_out;

  const dim3 blk(256);
  hipLaunchKernelGGL(p0_kernel, dim3(512), blk, 0, stream,
                     Wq, Wk, Wv, Wo, W1, W2, bq, bk, bv, wt, bqkv, x, xn1);
  hipLaunchKernelGGL((gemm_epi<0,128>), dim3(12, 64), blk, 0, stream,
                     xn1, wtqkv, bqkv, (const float*)nullptr, (void*)s1, 768, Dd);

  hipLaunchKernelGGL(attn_kernel, dim3(Nn / 256, Bb * Hh, SPLIT), blk, 0, stream,
                     s1, s2, s3, op0, op123, lp);
  hipLaunchKernelGGL(attn_combine, dim3((Bb * Hh * Nn * 4) / 256), blk, 0, stream,
                     op0, op123, lp, attnb);

  hipLaunchKernelGGL((gemm_epi<1,64>), dim3(4, 128), blk, 0, stream,
                     attnb, wto, bo, x, (void*)xsk, Dd, Dd);
  hipLaunchKernelGGL(ln_kernel, dim3(MT / 16), blk, 0, stream, xsk, xn2);
  hipLaunchKernelGGL((gemm_epi<2,128>), dim3(16, 64), blk, 0, stream,
                     xn2, wt1, b1, (const float*)nullptr, (void*)hid, DFFd, Dd);
  hipLaunchKernelGGL((gemm_epi<1,64>), dim3(4, 128), blk, 0, stream,
                     hid, wt2, b2, xsk, (void*)outp, Dd, DFFd);
}